// Round 1
// baseline (17598.286 us; speedup 1.0000x reference)
//
#include <hip/hip_runtime.h>
#include <hip/hip_bf16.h>

// Problem constants (fixed by the reference)
#define H_SHEET 150
#define W_SHEET 300
#define NN      (H_SHEET * W_SHEET)   // 45000
#define KSYN    32
#define KP1     33
#define NNZ     (NN * KP1)            // 1,485,000
#define BATCH   32
#define TSTEPS  100
#define NPAD    45056                 // N padded for alignment

// ---------------------------------------------------------------------------
// 1) Histogram of destination rows
__global__ __launch_bounds__(256) void hist_kernel(const int* __restrict__ rows,
                                                   int* __restrict__ counts) {
    int e = blockIdx.x * 256 + threadIdx.x;
    if (e < NNZ) atomicAdd(&counts[rows[e]], 1);
}

// ---------------------------------------------------------------------------
// 2) Exclusive scan of counts -> row_ptr (single block, 1024 threads)
__global__ __launch_bounds__(1024) void scan_kernel(const int* __restrict__ counts,
                                                    int* __restrict__ row_ptr) {
    __shared__ int wsum[16];
    __shared__ int carry_s;
    const int lane = threadIdx.x & 63;
    const int wid  = threadIdx.x >> 6;
    if (threadIdx.x == 0) carry_s = 0;
    __syncthreads();
    for (int base = 0; base < NN; base += 1024) {
        int i = base + threadIdx.x;
        int v = (i < NN) ? counts[i] : 0;
        int incl = v;
        #pragma unroll
        for (int d = 1; d < 64; d <<= 1) {
            int t = __shfl_up(incl, d, 64);
            if (lane >= d) incl += t;
        }
        if (lane == 63) wsum[wid] = incl;
        __syncthreads();
        if (wid == 0 && lane < 16) {
            int s = wsum[lane];
            #pragma unroll
            for (int d = 1; d < 16; d <<= 1) {
                int t = __shfl_up(s, d, 64);
                if (lane >= d) s += t;
            }
            wsum[lane] = s;
        }
        __syncthreads();
        int wprev = (wid > 0) ? wsum[wid - 1] : 0;
        int total = carry_s + wprev + incl;   // inclusive within global prefix
        if (i < NN) row_ptr[i + 1] = total;
        __syncthreads();
        if (threadIdx.x == 1023) carry_s += wsum[15];
        __syncthreads();
    }
    if (threadIdx.x == 0) row_ptr[0] = 0;
}

// ---------------------------------------------------------------------------
// 3) Scatter entries into CSR (col computed as e/33; cols input unused)
__global__ __launch_bounds__(256) void scatter_kernel(const int* __restrict__ rows,
                                                      const float* __restrict__ vals,
                                                      int* __restrict__ cursor,
                                                      int2* __restrict__ csr) {
    int e = blockIdx.x * 256 + threadIdx.x;
    if (e >= NNZ) return;
    int r = rows[e];
    int pos = atomicAdd(&cursor[r], 1);
    int col = e / KP1;                       // cols[e] == e/33 by construction
    csr[pos] = make_int2(col, __float_as_int(vals[e]));
}

// ---------------------------------------------------------------------------
// 4) h0 = x.T  : x is (B,N) row-major -> h (N,B)
__global__ __launch_bounds__(256) void init_kernel(const float* __restrict__ x,
                                                   float* __restrict__ h) {
    int idx = blockIdx.x * 256 + threadIdx.x;
    if (idx >= NN * BATCH) return;
    int n = idx >> 5;
    int b = idx & 31;
    h[idx] = x[b * NN + n];
}

// ---------------------------------------------------------------------------
// 5) One RNN step: gather spmm + bias + relu. 32 lanes per output row.
__global__ __launch_bounds__(256) void step_kernel(const int* __restrict__ row_ptr,
                                                   const int2* __restrict__ csr,
                                                   const float* __restrict__ bias,
                                                   const float* __restrict__ h_in,
                                                   float* __restrict__ h_out) {
    int gid = blockIdx.x * 256 + threadIdx.x;
    int r = gid >> 5;
    if (r >= NN) return;
    int b = gid & 31;
    int s = row_ptr[r];
    int e = row_ptr[r + 1];
    float acc = 0.f;
    for (; s < e; ++s) {
        int2 cv = csr[s];
        acc = fmaf(__int_as_float(cv.y), h_in[(cv.x << 5) + b], acc);
    }
    h_out[(r << 5) + b] = fmaxf(acc + bias[r], 0.f);
}

// ---------------------------------------------------------------------------
// 6) Split-K partial GEMM: hidden_pre[b][j] += sum_n h[n][b] * w1[n][j]
#define NCHUNK 512
__global__ __launch_bounds__(256) void gemm1_kernel(const float* __restrict__ h,
                                                    const float* __restrict__ w1,
                                                    float* __restrict__ acc) {
    int n0 = blockIdx.x * NCHUNK;
    int nend = n0 + NCHUNK; if (nend > NN) nend = NN;
    int j  = threadIdx.x & 63;
    int b0 = threadIdx.x >> 6;   // 0..3
    float sum[8];
    #pragma unroll
    for (int ii = 0; ii < 8; ++ii) sum[ii] = 0.f;
    for (int n = n0; n < nend; ++n) {
        float w = w1[n * 64 + j];
        #pragma unroll
        for (int ii = 0; ii < 8; ++ii)
            sum[ii] = fmaf(w, h[n * 32 + b0 + ii * 4], sum[ii]);
    }
    #pragma unroll
    for (int ii = 0; ii < 8; ++ii)
        atomicAdd(&acc[(b0 + ii * 4) * 64 + j], sum[ii]);
}

// ---------------------------------------------------------------------------
// 7) Head: out[b][oj] = b2[oj] + sum_k relu(acc[b][k]+b1[k]) * w2[k][oj]
__global__ __launch_bounds__(320) void head_kernel(const float* __restrict__ acc,
                                                   const float* __restrict__ b1,
                                                   const float* __restrict__ w2,
                                                   const float* __restrict__ b2,
                                                   float* __restrict__ out) {
    int t = threadIdx.x;
    if (t >= 320) return;
    int b = t / 10, oj = t % 10;
    float s = b2[oj];
    #pragma unroll
    for (int k = 0; k < 64; ++k)
        s += fmaxf(acc[b * 64 + k] + b1[k], 0.f) * w2[k * 10 + oj];
    out[b * 10 + oj] = s;
}

// ---------------------------------------------------------------------------
extern "C" void kernel_launch(void* const* d_in, const int* in_sizes, int n_in,
                              void* d_out, int out_size, void* d_ws, size_t ws_size,
                              hipStream_t stream) {
    const float* x    = (const float*)d_in[0];
    const float* vals = (const float*)d_in[1];
    const float* bias = (const float*)d_in[2];
    const float* w1   = (const float*)d_in[3];
    const float* b1   = (const float*)d_in[4];
    const float* w2   = (const float*)d_in[5];
    const float* b2   = (const float*)d_in[6];
    const int*   rows = (const int*)d_in[7];
    float* out = (float*)d_out;

    // workspace layout
    const int NB = NN * BATCH;                    // 1,440,000 floats
    float* hA      = (float*)d_ws;
    float* hB      = hA + NB;
    int*   row_ptr = (int*)(hB + NB);             // NPAD ints
    int*   cursor  = row_ptr + NPAD;              // NPAD ints (also histogram counts)
    int2*  csr     = (int2*)(cursor + NPAD);      // NNZ int2 (8B-aligned)
    float* acc     = (float*)(csr + NNZ);         // 32*64 floats

    // ---- CSR-transpose build ----
    hipMemsetAsync(cursor, 0, NN * sizeof(int), stream);
    hist_kernel<<<(NNZ + 255) / 256, 256, 0, stream>>>(rows, cursor);
    scan_kernel<<<1, 1024, 0, stream>>>(cursor, row_ptr);
    hipMemcpyAsync(cursor, row_ptr, NN * sizeof(int), hipMemcpyDeviceToDevice, stream);
    scatter_kernel<<<(NNZ + 255) / 256, 256, 0, stream>>>(rows, vals, cursor, csr);

    // ---- h0 = x.T ----
    init_kernel<<<(NB + 255) / 256, 256, 0, stream>>>(x, hA);

    // ---- T recurrent steps ----
    float* bufs[2] = { hA, hB };
    for (int t = 0; t < TSTEPS; ++t) {
        step_kernel<<<(NN * BATCH) / 256, 256, 0, stream>>>(
            row_ptr, csr, bias, bufs[t & 1], bufs[(t + 1) & 1]);
    }
    float* hfin = bufs[TSTEPS & 1];

    // ---- MLP head ----
    hipMemsetAsync(acc, 0, 32 * 64 * sizeof(float), stream);
    gemm1_kernel<<<(NN + NCHUNK - 1) / NCHUNK, 256, 0, stream>>>(hfin, w1, acc);
    head_kernel<<<1, 320, 0, stream>>>(acc, b1, w2, b2, out);
}

// Round 2
// 5458.699 us; speedup vs baseline: 3.2239x; 3.2239x over previous
//
#include <hip/hip_runtime.h>
#include <hip/hip_bf16.h>

// Problem constants (fixed by the reference)
#define H_SHEET 150
#define W_SHEET 300
#define NN      (H_SHEET * W_SHEET)   // 45000
#define KSYN    32
#define KP1     33
#define NNZ     (NN * KP1)            // 1,485,000
#define BATCH   32
#define TSTEPS  100
#define NPAD    45056                 // N padded for alignment
#define NCHUNK  64
#define NPART   ((NN + NCHUNK - 1) / NCHUNK)   // 704

// ---------------------------------------------------------------------------
// bijective XCD swizzle (8 XCDs): contiguous grid chunk per XCD
__device__ inline int xcd_swizzle(int bid, int nwg) {
    int q = nwg >> 3, r = nwg & 7;
    int xcd = bid & 7, idx = bid >> 3;
    return (xcd < r ? xcd * (q + 1) : r * (q + 1) + (xcd - r) * q) + idx;
}

// ---------------------------------------------------------------------------
// 1) Histogram of destination rows
__global__ __launch_bounds__(256) void hist_kernel(const int* __restrict__ rows,
                                                   int* __restrict__ counts) {
    int e = blockIdx.x * 256 + threadIdx.x;
    if (e < NNZ) atomicAdd(&counts[rows[e]], 1);
}

// ---------------------------------------------------------------------------
// 2) Exclusive scan of counts -> row_ptr (single block, 1024 threads)
__global__ __launch_bounds__(1024) void scan_kernel(const int* __restrict__ counts,
                                                    int* __restrict__ row_ptr) {
    __shared__ int wsum[16];
    __shared__ int carry_s;
    const int lane = threadIdx.x & 63;
    const int wid  = threadIdx.x >> 6;
    if (threadIdx.x == 0) carry_s = 0;
    __syncthreads();
    for (int base = 0; base < NN; base += 1024) {
        int i = base + threadIdx.x;
        int v = (i < NN) ? counts[i] : 0;
        int incl = v;
        #pragma unroll
        for (int d = 1; d < 64; d <<= 1) {
            int t = __shfl_up(incl, d, 64);
            if (lane >= d) incl += t;
        }
        if (lane == 63) wsum[wid] = incl;
        __syncthreads();
        if (wid == 0 && lane < 16) {
            int s = wsum[lane];
            #pragma unroll
            for (int d = 1; d < 16; d <<= 1) {
                int t = __shfl_up(s, d, 64);
                if (lane >= d) s += t;
            }
            wsum[lane] = s;
        }
        __syncthreads();
        int wprev = (wid > 0) ? wsum[wid - 1] : 0;
        int total = carry_s + wprev + incl;
        if (i < NN) row_ptr[i + 1] = total;
        __syncthreads();
        if (threadIdx.x == 1023) carry_s += wsum[15];
        __syncthreads();
    }
    if (threadIdx.x == 0) row_ptr[0] = 0;
}

// ---------------------------------------------------------------------------
// 3) Scatter entries into CSR (col computed as e/33; cols input unused)
__global__ __launch_bounds__(256) void scatter_kernel(const int* __restrict__ rows,
                                                      const float* __restrict__ vals,
                                                      int* __restrict__ cursor,
                                                      int2* __restrict__ csr) {
    int e = blockIdx.x * 256 + threadIdx.x;
    if (e >= NNZ) return;
    int r = rows[e];
    int pos = atomicAdd(&cursor[r], 1);
    int col = e / KP1;
    csr[pos] = make_int2(col, __float_as_int(vals[e]));
}

// ---------------------------------------------------------------------------
// 4) h0 = x.T via LDS tile transpose: x (B,N) -> h (N,B). Tile 64n x 32b.
__global__ __launch_bounds__(256) void init_kernel(const float* __restrict__ x,
                                                   float* __restrict__ h) {
    __shared__ float tile[64 * 33];
    int n0 = blockIdx.x * 64;
    int tn = threadIdx.x & 63;          // n offset within tile
    int tb = threadIdx.x >> 6;          // 0..3
    #pragma unroll
    for (int p = 0; p < 8; ++p) {
        int b = tb + p * 4;
        int n = n0 + tn;
        float v = (n < NN) ? x[b * NN + n] : 0.f;
        tile[tn * 33 + b] = v;
    }
    __syncthreads();
    int b2 = threadIdx.x & 31;
    int nb = threadIdx.x >> 5;          // 0..7
    #pragma unroll
    for (int p = 0; p < 8; ++p) {
        int n = n0 + nb + p * 8;
        if (n < NN) h[n * 32 + b2] = tile[(nb + p * 8) * 33 + b2];
    }
}

// ---------------------------------------------------------------------------
// 5) One RNN step. 8 lanes per row, float4 over batch, entry-unroll x4.
#define ROWS_PER_BLOCK 32
#define STEP_GRID ((NN + ROWS_PER_BLOCK - 1) / ROWS_PER_BLOCK)   // 1407
__global__ __launch_bounds__(256) void step_kernel(const int* __restrict__ row_ptr,
                                                   const int2* __restrict__ csr,
                                                   const float* __restrict__ bias,
                                                   const float* __restrict__ h_in,
                                                   float* __restrict__ h_out) {
    int blk = xcd_swizzle(blockIdx.x, STEP_GRID);
    int r = blk * ROWS_PER_BLOCK + (threadIdx.x >> 3);
    if (r >= NN) return;
    int bo = (threadIdx.x & 7) * 4;     // batch offset, 16B-aligned

    int s = row_ptr[r];
    int e = row_ptr[r + 1];
    int n = e - s;
    const int2* p = csr + s;

    float4 acc = make_float4(0.f, 0.f, 0.f, 0.f);
    int i = 0;
    for (; i + 4 <= n; i += 4) {
        int2 c0 = p[i];
        int2 c1 = p[i + 1];
        int2 c2 = p[i + 2];
        int2 c3 = p[i + 3];
        float4 h0 = *(const float4*)&h_in[(c0.x << 5) + bo];
        float4 h1 = *(const float4*)&h_in[(c1.x << 5) + bo];
        float4 h2 = *(const float4*)&h_in[(c2.x << 5) + bo];
        float4 h3 = *(const float4*)&h_in[(c3.x << 5) + bo];
        float v0 = __int_as_float(c0.y);
        float v1 = __int_as_float(c1.y);
        float v2 = __int_as_float(c2.y);
        float v3 = __int_as_float(c3.y);
        acc.x = fmaf(v0, h0.x, acc.x); acc.y = fmaf(v0, h0.y, acc.y);
        acc.z = fmaf(v0, h0.z, acc.z); acc.w = fmaf(v0, h0.w, acc.w);
        acc.x = fmaf(v1, h1.x, acc.x); acc.y = fmaf(v1, h1.y, acc.y);
        acc.z = fmaf(v1, h1.z, acc.z); acc.w = fmaf(v1, h1.w, acc.w);
        acc.x = fmaf(v2, h2.x, acc.x); acc.y = fmaf(v2, h2.y, acc.y);
        acc.z = fmaf(v2, h2.z, acc.z); acc.w = fmaf(v2, h2.w, acc.w);
        acc.x = fmaf(v3, h3.x, acc.x); acc.y = fmaf(v3, h3.y, acc.y);
        acc.z = fmaf(v3, h3.z, acc.z); acc.w = fmaf(v3, h3.w, acc.w);
    }
    for (; i < n; ++i) {
        int2 c = p[i];
        float4 hv = *(const float4*)&h_in[(c.x << 5) + bo];
        float v = __int_as_float(c.y);
        acc.x = fmaf(v, hv.x, acc.x); acc.y = fmaf(v, hv.y, acc.y);
        acc.z = fmaf(v, hv.z, acc.z); acc.w = fmaf(v, hv.w, acc.w);
    }
    float bv = bias[r];
    float4 o;
    o.x = fmaxf(acc.x + bv, 0.f);
    o.y = fmaxf(acc.y + bv, 0.f);
    o.z = fmaxf(acc.z + bv, 0.f);
    o.w = fmaxf(acc.w + bv, 0.f);
    *(float4*)&h_out[(r << 5) + bo] = o;
}

// ---------------------------------------------------------------------------
// 6a) Split-K GEMM partials: partial[blk][b*64+j] = sum_{n in chunk} h[n][b]*w1[n][j]
__global__ __launch_bounds__(256) void gemm1_kernel(const float* __restrict__ h,
                                                    const float* __restrict__ w1,
                                                    float* __restrict__ partials) {
    int n0 = blockIdx.x * NCHUNK;
    int nend = n0 + NCHUNK; if (nend > NN) nend = NN;
    int j  = threadIdx.x & 63;
    int b0 = threadIdx.x >> 6;   // 0..3
    float sum[8];
    #pragma unroll
    for (int ii = 0; ii < 8; ++ii) sum[ii] = 0.f;
    for (int n = n0; n < nend; ++n) {
        float w = w1[n * 64 + j];
        #pragma unroll
        for (int ii = 0; ii < 8; ++ii)
            sum[ii] = fmaf(w, h[n * 32 + b0 + ii * 4], sum[ii]);
    }
    float* dst = partials + blockIdx.x * 2048;
    #pragma unroll
    for (int ii = 0; ii < 8; ++ii)
        dst[(b0 + ii * 4) * 64 + j] = sum[ii];
}

// 6b) Reduce partials -> acc (2048 cells)
__global__ __launch_bounds__(256) void gemm1_reduce(const float* __restrict__ partials,
                                                    float* __restrict__ acc) {
    int cell = blockIdx.x * 256 + threadIdx.x;   // 8 blocks x 256 = 2048
    float s0 = 0.f, s1 = 0.f, s2 = 0.f, s3 = 0.f;
    int k = 0;
    for (; k + 4 <= NPART; k += 4) {
        s0 += partials[(k + 0) * 2048 + cell];
        s1 += partials[(k + 1) * 2048 + cell];
        s2 += partials[(k + 2) * 2048 + cell];
        s3 += partials[(k + 3) * 2048 + cell];
    }
    for (; k < NPART; ++k) s0 += partials[k * 2048 + cell];
    acc[cell] = (s0 + s1) + (s2 + s3);
}

// ---------------------------------------------------------------------------
// 7) Head: out[b][oj] = b2[oj] + sum_k relu(acc[b][k]+b1[k]) * w2[k][oj]
__global__ __launch_bounds__(320) void head_kernel(const float* __restrict__ acc,
                                                   const float* __restrict__ b1,
                                                   const float* __restrict__ w2,
                                                   const float* __restrict__ b2,
                                                   float* __restrict__ out) {
    int t = threadIdx.x;
    if (t >= 320) return;
    int b = t / 10, oj = t % 10;
    float s = b2[oj];
    #pragma unroll
    for (int k = 0; k < 64; ++k)
        s += fmaxf(acc[b * 64 + k] + b1[k], 0.f) * w2[k * 10 + oj];
    out[b * 10 + oj] = s;
}

// ---------------------------------------------------------------------------
extern "C" void kernel_launch(void* const* d_in, const int* in_sizes, int n_in,
                              void* d_out, int out_size, void* d_ws, size_t ws_size,
                              hipStream_t stream) {
    const float* x    = (const float*)d_in[0];
    const float* vals = (const float*)d_in[1];
    const float* bias = (const float*)d_in[2];
    const float* w1   = (const float*)d_in[3];
    const float* b1   = (const float*)d_in[4];
    const float* w2   = (const float*)d_in[5];
    const float* b2   = (const float*)d_in[6];
    const int*   rows = (const int*)d_in[7];
    float* out = (float*)d_out;

    // workspace layout
    const int NB = NN * BATCH;                    // 1,440,000 floats
    float* hA       = (float*)d_ws;
    float* hB       = hA + NB;
    int*   row_ptr  = (int*)(hB + NB);            // NPAD ints
    int*   cursor   = row_ptr + NPAD;             // NPAD ints
    int2*  csr      = (int2*)(cursor + NPAD);     // NNZ int2 (8B-aligned)
    float* partials = (float*)(csr + NNZ);        // NPART*2048 floats
    float* acc      = partials + NPART * 2048;    // 2048 floats

    // ---- CSR-transpose build ----
    hipMemsetAsync(cursor, 0, NN * sizeof(int), stream);
    hist_kernel<<<(NNZ + 255) / 256, 256, 0, stream>>>(rows, cursor);
    scan_kernel<<<1, 1024, 0, stream>>>(cursor, row_ptr);
    hipMemcpyAsync(cursor, row_ptr, NN * sizeof(int), hipMemcpyDeviceToDevice, stream);
    scatter_kernel<<<(NNZ + 255) / 256, 256, 0, stream>>>(rows, vals, cursor, csr);

    // ---- h0 = x.T ----
    init_kernel<<<(NN + 63) / 64, 256, 0, stream>>>(x, hA);

    // ---- T recurrent steps ----
    float* bufs[2] = { hA, hB };
    for (int t = 0; t < TSTEPS; ++t) {
        step_kernel<<<STEP_GRID, 256, 0, stream>>>(
            row_ptr, csr, bias, bufs[t & 1], bufs[(t + 1) & 1]);
    }
    float* hfin = bufs[TSTEPS & 1];

    // ---- MLP head ----
    gemm1_kernel<<<NPART, 256, 0, stream>>>(hfin, w1, partials);
    gemm1_reduce<<<8, 256, 0, stream>>>(partials, acc);
    head_kernel<<<1, 320, 0, stream>>>(acc, b1, w2, b2, out);
}